// Round 1
// baseline (397.063 us; speedup 1.0000x reference)
//
#include <hip/hip_runtime.h>

// Problem constants (HyperNetwork_9990093931021)
#define BB 256   // batch
#define CC 512   // channels
#define NZ 256   // flattened spatial (16*16)
#define ZD 64    // z_dim
#define KK 9     // out_c * f * f = 1*3*3

// ---- DPP cross-lane add helpers (VALU-only, no LDS pipe) ----
template<int CTRL>
__device__ __forceinline__ float dpp_add(float v) {
    int o = __builtin_amdgcn_update_dpp(0, __float_as_int(v), CTRL, 0xF, 0xF, true);
    return v + __int_as_float(o);
}
// sum over aligned 8-lane group: xor1 (quad_perm 1,0,3,2), xor2 (quad_perm 2,3,0,1),
// then row_half_mirror combines the two quads of the 8-lane half-row.
__device__ __forceinline__ float red8(float v) {
    v = dpp_add<0xB1>(v);   // quad_perm [1,0,3,2]
    v = dpp_add<0x4E>(v);   // quad_perm [2,3,0,1]
    v = dpp_add<0x141>(v);  // row_half_mirror
    return v;
}

__global__ __launch_bounds__(512, 4)  // 8 waves/block, 4 waves/EU -> 2 blocks/CU
void hyper_kernel(const float* __restrict__ z,
                  const float* __restrict__ W_in,
                  const float* __restrict__ b_in,
                  const float* __restrict__ W_out,
                  const float* __restrict__ b_out,
                  float* __restrict__ out) {
    // LDS: fused weight WfT[k][n] + W_out transposed + biases  (~12 KB total)
    __shared__ __align__(16) float s_wfT[KK * NZ];   // [k][n]
    __shared__ __align__(16) float s_woutT[KK * ZD]; // [k][z]
    __shared__ float s_bin[ZD];
    __shared__ float s_biask[KK];

    const int c = blockIdx.x;
    const int t = threadIdx.x;

    // ---- stage W_out (transposed) and biases ----
    for (int i = t; i < KK * ZD; i += 512) {          // 576 elems, 512 threads
        float v = W_out[i];                            // coalesced
        int zz = i / KK, k = i - zz * KK;
        s_woutT[k * ZD + zz] = v;
    }
    if (t < ZD) s_bin[t] = b_in[c * ZD + t];
    __syncthreads();

    // ---- phase 1: WfT[k][n] = sum_z W_in[c,n,z] * W_out[z,k] ----
    {
        const int n = t >> 1, half = t & 1;            // 2 threads per n, 32 z each
        const float* wrow = W_in + ((size_t)c * NZ + n) * ZD + half * 32;
        float4 w[8];
#pragma unroll
        for (int j = 0; j < 8; ++j)
            w[j] = *reinterpret_cast<const float4*>(wrow + 4 * j); // one 128B line/lane
        float acc[KK];
#pragma unroll
        for (int k = 0; k < KK; ++k) acc[k] = 0.f;
#pragma unroll
        for (int j = 0; j < 8; ++j) {
#pragma unroll
            for (int k = 0; k < KK; ++k) {
                const float4 wo = *reinterpret_cast<const float4*>(
                    &s_woutT[k * ZD + half * 32 + 4 * j]);         // 2-addr broadcast
                acc[k] += w[j].x * wo.x + w[j].y * wo.y + w[j].z * wo.z + w[j].w * wo.w;
            }
        }
#pragma unroll
        for (int k = 0; k < KK; ++k) acc[k] = dpp_add<0xB1>(acc[k]); // combine half 0+1
        if (half == 0) {
#pragma unroll
            for (int k = 0; k < KK; ++k) s_wfT[k * NZ + n] = acc[k];
        }
        if (t < KK) { // fused bias: b_in[c] . W_out[:,k] + b_out[k]
            float s = 0.f;
            for (int zz = 0; zz < ZD; ++zz) s += s_bin[zz] * s_woutT[t * ZD + zz];
            s_biask[t] = s + b_out[t];
        }
    }
    __syncthreads();

    // ---- phase 2: out[b,c,k] = z[b,c,:] . WfT[k][:] + biask[k] ----
    const int lane = t & 63;
    const int wave = t >> 6;
    const int g = lane >> 3;   // 8 groups of 8 lanes; group owns 2 consecutive b
    const int sub = lane & 7;  // lane's slice of the n-dimension
    const float biasS = s_biask[sub];
    const float bias8 = s_biask[8];

#pragma unroll 1
    for (int iter = 0; iter < 2; ++iter) {
        const int b0 = iter * 128 + wave * 16 + g * 2;
        const float* xp = z + ((size_t)b0 * CC + c) * NZ;
        float4 x0[8], x1[8];
#pragma unroll
        for (int j = 0; j < 8; ++j)   // group of 8 lanes covers a full 128B line per j
            x0[j] = *reinterpret_cast<const float4*>(xp + (sub + 8 * j) * 4);
#pragma unroll
        for (int j = 0; j < 8; ++j)
            x1[j] = *reinterpret_cast<const float4*>(xp + (size_t)CC * NZ + (sub + 8 * j) * 4);

        float a0[KK], a1[KK];
#pragma unroll
        for (int k = 0; k < KK; ++k) { a0[k] = 0.f; a1[k] = 0.f; }
#pragma unroll
        for (int k = 0; k < KK; ++k) {
#pragma unroll
            for (int j = 0; j < 8; ++j) {
                const float4 wf = *reinterpret_cast<const float4*>(
                    &s_wfT[k * NZ + (sub + 8 * j) * 4]); // 128B span + group broadcast
                a0[k] += x0[j].x * wf.x + x0[j].y * wf.y + x0[j].z * wf.z + x0[j].w * wf.w;
                a1[k] += x1[j].x * wf.x + x1[j].y * wf.y + x1[j].z * wf.z + x1[j].w * wf.w;
            }
        }
#pragma unroll
        for (int k = 0; k < KK; ++k) { a0[k] = red8(a0[k]); a1[k] = red8(a1[k]); }

        // lane sub stores k=sub (0..7); sub==0 also stores k=8
        float v0 = a0[0], v1 = a1[0];
#pragma unroll
        for (int k = 1; k < 8; ++k) {
            if (sub == k) { v0 = a0[k]; v1 = a1[k]; }  // cndmask chain
        }
        v0 += biasS; v1 += biasS;
        const size_t o0 = ((size_t)b0 * CC + c) * KK;
        out[o0 + sub] = v0;
        out[o0 + (size_t)CC * KK + sub] = v1;
        if (sub == 0) {
            out[o0 + 8] = a0[8] + bias8;
            out[o0 + (size_t)CC * KK + 8] = a1[8] + bias8;
        }
    }
}

extern "C" void kernel_launch(void* const* d_in, const int* in_sizes, int n_in,
                              void* d_out, int out_size, void* d_ws, size_t ws_size,
                              hipStream_t stream) {
    const float* z     = (const float*)d_in[0];
    const float* W_in  = (const float*)d_in[1];
    const float* b_in  = (const float*)d_in[2];
    const float* W_out = (const float*)d_in[3];
    const float* b_out = (const float*)d_in[4];
    float* out = (float*)d_out;
    hyper_kernel<<<dim3(CC), dim3(512), 0, stream>>>(z, W_in, b_in, W_out, b_out, out);
}

// Round 2
// 227.608 us; speedup vs baseline: 1.7445x; 1.7445x over previous
//
#include <hip/hip_runtime.h>

// Problem constants (HyperNetwork_9990093931021)
#define BB 256   // batch
#define CC 512   // channels
#define NZ 256   // flattened spatial (16*16)
#define ZD 64    // z_dim
#define KK 9     // out_c * f * f = 1*3*3

// ---- DPP cross-lane add helpers (VALU-only, no LDS pipe) ----
template<int CTRL>
__device__ __forceinline__ float dpp_add(float v) {
    int o = __builtin_amdgcn_update_dpp(0, __float_as_int(v), CTRL, 0xF, 0xF, true);
    return v + __int_as_float(o);
}
// sum over aligned 8-lane group
__device__ __forceinline__ float red8(float v) {
    v = dpp_add<0xB1>(v);   // quad_perm [1,0,3,2]  (xor 1)
    v = dpp_add<0x4E>(v);   // quad_perm [2,3,0,1]  (xor 2)
    v = dpp_add<0x141>(v);  // row_half_mirror      (combine quads of 8-lane half)
    return v;
}

// block = 512 threads (8 waves), grid = C = 512 blocks.
// launch_bounds min-waves/EU = 2 -> 256 VGPR cap; actual usage ~100 -> no spills,
// HW occupancy still 4 waves/EU from actual allocation.
__global__ __launch_bounds__(512, 2)
void hyper_kernel(const float* __restrict__ z,
                  const float* __restrict__ W_in,
                  const float* __restrict__ b_in,
                  const float* __restrict__ W_out,
                  const float* __restrict__ b_out,
                  float* __restrict__ out) {
    __shared__ __align__(16) float s_wfT[KK * NZ];   // fused weight, [k][n]
    __shared__ __align__(16) float s_woutT[KK * ZD]; // W_out transposed, [k][z]
    __shared__ float s_bin[ZD];
    __shared__ float s_biask[KK];

    const int c = blockIdx.x;
    const int t = threadIdx.x;

    // ---- stage W_out (transposed) and b_in ----
    for (int i = t; i < KK * ZD; i += 512) {
        float v = W_out[i];
        int zz = i / KK, k = i - zz * KK;
        s_woutT[k * ZD + zz] = v;
    }
    if (t < ZD) s_bin[t] = b_in[c * ZD + t];
    __syncthreads();

    // ---- phase 1: WfT[k][n] = sum_z W_in[c,n,z] * W_out[z,k] ----
    {
        const int n = t >> 1, half = t & 1;            // 2 threads per n, 32 z each
        const float* wrow = W_in + ((size_t)c * NZ + n) * ZD + half * 32;
        float acc[KK];
#pragma unroll
        for (int k = 0; k < KK; ++k) acc[k] = 0.f;
#pragma unroll
        for (int j = 0; j < 8; ++j) {
            const float4 w = *reinterpret_cast<const float4*>(wrow + 4 * j);
#pragma unroll
            for (int k = 0; k < KK; ++k) {
                const float4 wo = *reinterpret_cast<const float4*>(
                    &s_woutT[k * ZD + half * 32 + 4 * j]);     // 2-addr broadcast
                acc[k] += w.x * wo.x + w.y * wo.y + w.z * wo.z + w.w * wo.w;
            }
        }
#pragma unroll
        for (int k = 0; k < KK; ++k) acc[k] = dpp_add<0xB1>(acc[k]); // half0+half1
        if (half == 0) {
#pragma unroll
            for (int k = 0; k < KK; ++k) s_wfT[k * NZ + n] = acc[k];
        }
        if (t < KK) { // fused bias: b_in[c] . W_out[:,k] + b_out[k]
            float s = 0.f;
            for (int zz = 0; zz < ZD; ++zz) s += s_bin[zz] * s_woutT[t * ZD + zz];
            s_biask[t] = s + b_out[t];
        }
    }
    __syncthreads();

    // ---- phase 2: out[b,c,k] = z[b,c,:] . WfT[k][:] + biask[k] ----
    // 8-lane group owns 4 consecutive b; wave = 32 b; 8 waves = 256 b (one pass).
    const int lane = t & 63;
    const int wave = t >> 6;
    const int g = lane >> 3;
    const int sub = lane & 7;            // lane's slice of the n dimension
    const int b0 = wave * 32 + g * 4;
    const float biasS = s_biask[sub];
    const float bias8 = s_biask[8];

    const float* xp = z + ((size_t)b0 * CC + c) * NZ + sub * 4; // lane base
    const size_t bstr = (size_t)CC * NZ;                        // b stride (floats)

    float acc[4][KK];
#pragma unroll
    for (int bb = 0; bb < 4; ++bb)
#pragma unroll
        for (int k = 0; k < KK; ++k) acc[bb][k] = 0.f;

    // double-buffered z stream: 8 float4 live (not 64 regs like R1)
    float4 xb[2][4];
#pragma unroll
    for (int bb = 0; bb < 4; ++bb)
        xb[0][bb] = *reinterpret_cast<const float4*>(xp + bb * bstr);

#pragma unroll
    for (int j = 0; j < 8; ++j) {
        if (j < 7) {
#pragma unroll
            for (int bb = 0; bb < 4; ++bb)
                xb[(j + 1) & 1][bb] =
                    *reinterpret_cast<const float4*>(xp + bb * bstr + (j + 1) * 32);
        }
#pragma unroll
        for (int k = 0; k < KK; ++k) {
            const float4 wf = *reinterpret_cast<const float4*>(
                &s_wfT[k * NZ + sub * 4 + j * 32]);   // 128B span, group-broadcast
#pragma unroll
            for (int bb = 0; bb < 4; ++bb) {
                const float4 x = xb[j & 1][bb];
                acc[bb][k] += x.x * wf.x + x.y * wf.y + x.z * wf.z + x.w * wf.w;
            }
        }
    }

#pragma unroll
    for (int bb = 0; bb < 4; ++bb)
#pragma unroll
        for (int k = 0; k < KK; ++k) acc[bb][k] = red8(acc[bb][k]);

#pragma unroll
    for (int bb = 0; bb < 4; ++bb) {
        float v = acc[bb][0];
#pragma unroll
        for (int k = 1; k < 8; ++k) {
            if (sub == k) v = acc[bb][k];   // cndmask chain
        }
        const size_t o0 = ((size_t)(b0 + bb) * CC + c) * KK;
        out[o0 + sub] = v + biasS;
        if (sub == 0) out[o0 + 8] = acc[bb][8] + bias8;
    }
}

extern "C" void kernel_launch(void* const* d_in, const int* in_sizes, int n_in,
                              void* d_out, int out_size, void* d_ws, size_t ws_size,
                              hipStream_t stream) {
    const float* z     = (const float*)d_in[0];
    const float* W_in  = (const float*)d_in[1];
    const float* b_in  = (const float*)d_in[2];
    const float* W_out = (const float*)d_in[3];
    const float* b_out = (const float*)d_in[4];
    float* out = (float*)d_out;
    hyper_kernel<<<dim3(CC), dim3(512), 0, stream>>>(z, W_in, b_in, W_out, b_out, out);
}